// Round 1
// baseline (10940.708 us; speedup 1.0000x reference)
//
#include <hip/hip_runtime.h>
#include <math.h>

// Problem constants
#define NB 8
#define NH 256
#define NW 256
#define NC 180     // channels
#define NE 6       // heads
#define HD 30      // head dim
#define NL 256     // tokens per window (16x16)
#define NK 64      // selected tokens per head
#define NWIN 2048  // number of windows

// ---------------------------------------------------------------------------
// Kernel 1: router logits + sigmoid + top-64 (incl. token 0) per (window,head)
// grid 2048 x 256 threads
// ---------------------------------------------------------------------------
__global__ __launch_bounds__(256) void k_router_topk(
    const float* __restrict__ x, const float* __restrict__ Wr,
    int* __restrict__ idx_g, float* __restrict__ vals_g)
{
    __shared__ float wr_s[NE * NC];      // 1080
    __shared__ float xs[32 * 181];       // tile of 32 tokens, padded stride
    __shared__ float lg[NE * NL];        // sigmoid logits [head][token]

    const int w   = blockIdx.x;
    const int tid = threadIdx.x;
    const int b = w >> 8, hb = (w >> 4) & 15, wb = w & 15;
    const long win_base = (((long)b * NH + hb * 16) * NW + wb * 16) * NC;

    for (int f = tid; f < NE * NC; f += 256) wr_s[f] = Wr[f];
    __syncthreads();

    // logits in tiles of 32 tokens
    for (int tile = 0; tile < 8; ++tile) {
        for (int f = tid; f < 32 * NC; f += 256) {
            int tl = f / NC, ch = f % NC;
            int tok = tile * 32 + tl;
            int r = tok >> 4, cl = tok & 15;
            xs[tl * 181 + ch] = x[win_base + ((long)r * NW + cl) * NC + ch];
        }
        __syncthreads();
        if (tid < 192) {
            int tl = tid & 31, e = tid >> 5;   // e uniform per 32 threads
            float acc = 0.f;
            for (int c = 0; c < NC; ++c) acc += xs[tl * 181 + c] * wr_s[e * NC + c];
            lg[e * NL + tile * 32 + tl] = 1.0f / (1.0f + expf(-acc));
        }
        __syncthreads();
    }

    // top-(k-1) over tokens 1..255 by rank-counting; token 0 always slot 0.
    // tie-break: equal values -> lower index wins (matches jax.lax.top_k).
    for (int e = 0; e < NE; ++e) {
        float vt = lg[e * NL + tid];
        if (tid == 0) {
            idx_g[(w * NE + e) * NK]  = 0;
            vals_g[(w * NE + e) * NK] = vt;
        } else {
            int rank = 0;
            for (int j = 1; j < NL; ++j) {
                float vj = lg[e * NL + j];
                rank += (vj > vt) || (vj == vt && j < tid);
            }
            if (rank < NK - 1) {
                idx_g[(w * NE + e) * NK + 1 + rank]  = tid;
                vals_g[(w * NE + e) * NK + 1 + rank] = vt;
            }
        }
    }
}

// ---------------------------------------------------------------------------
// Kernel 2: per-window expert attention + scatter into y (window layout)
// grid 2048 x 512 threads, dynamic LDS
//   phase A (per head): gather Xg -> QKV -> scores -> softmax -> PV*gate
//   phase B (per channel half): pre = attn @ Wo, scatter-add in LDS, store y
// ---------------------------------------------------------------------------
// LDS float offsets
#define ATT_OFF 0                 // attn_all: 6*64 rows, stride 31 -> 11904
#define IDX_OFF 11904             // 384 ints
#define VAL_OFF 12288             // 384 floats
#define REG_OFF 12672             // region: max(phaseA 21568, acc 256*91=23296)
#define XG_OFF  (REG_OFF + 0)     // 64*181 = 11584
#define QKV_OFF (REG_OFF + 11584) // 64*91  = 5824
#define SC_OFF  (REG_OFF + 17408) // 64*65  = 4160
#define K2_LDS_FLOATS (REG_OFF + 23296)   // 35968 floats = 143872 B

__global__ __launch_bounds__(512) void k_attn(
    const float* __restrict__ x, const float* __restrict__ Wqkv,
    const float* __restrict__ Wo,
    const int* __restrict__ idx_g, const float* __restrict__ vals_g,
    float* __restrict__ y)
{
    extern __shared__ float sm[];
    float* attn_all = sm + ATT_OFF;
    int*   idx_s    = (int*)(sm + IDX_OFF);
    float* vals_s   = sm + VAL_OFF;

    const int w   = blockIdx.x;
    const int tid = threadIdx.x;
    const int b = w >> 8, hb = (w >> 4) & 15, wb = w & 15;
    const long win_base = (((long)b * NH + hb * 16) * NW + wb * 16) * NC;

    for (int f = tid; f < NE * NK; f += 512) {
        idx_s[f]  = idx_g[w * NE * NK + f];
        vals_s[f] = vals_g[w * NE * NK + f];
    }
    __syncthreads();

    const int lane_i = tid & 63;   // token slot / row
    const int jg     = tid >> 6;   // 0..7, uniform per wave

    // ---------------- phase A ----------------
    for (int h = 0; h < NE; ++h) {
        // gather selected tokens (float4)
        for (int f = tid; f < NK * (NC / 4); f += 512) {
            int j = f / (NC / 4), q = f % (NC / 4);
            int tok = idx_s[h * NK + j];
            int r = tok >> 4, cl = tok & 15;
            const float4 v = *(const float4*)(x + win_base + ((long)r * NW + cl) * NC + q * 4);
            float* dst = sm + XG_OFF + j * 181 + q * 4;
            dst[0] = v.x; dst[1] = v.y; dst[2] = v.z; dst[3] = v.w;
        }
        __syncthreads();

        // QKV: out (64 tokens x 90), thread = (lane_i, cols jg*12..)
        {
            const int j0 = jg * 12;
            float acc[12];
            #pragma unroll
            for (int jj = 0; jj < 12; ++jj) acc[jj] = 0.f;
            const float* wq = Wqkv + h * NC * 90;
            for (int c = 0; c < NC; ++c) {
                float xv = sm[XG_OFF + lane_i * 181 + c];
                const float2* wq2 = (const float2*)(wq + c * 90 + j0);
                #pragma unroll
                for (int jj = 0; jj < 6; ++jj) {
                    if (j0 + 2 * jj < 90) {
                        float2 wv = wq2[jj];
                        acc[2 * jj]     += xv * wv.x;
                        acc[2 * jj + 1] += xv * wv.y;
                    }
                }
            }
            #pragma unroll
            for (int jj = 0; jj < 12; ++jj)
                if (j0 + jj < 90) sm[QKV_OFF + lane_i * 91 + j0 + jj] = acc[jj];
        }
        __syncthreads();

        // scores = Q K^T / sqrt(30): thread = (row lane_i, cols jg*8..)
        {
            const int j0 = jg * 8;
            float acc[8];
            #pragma unroll
            for (int jj = 0; jj < 8; ++jj) acc[jj] = 0.f;
            for (int d = 0; d < HD; ++d) {
                float q = sm[QKV_OFF + lane_i * 91 + d];
                #pragma unroll
                for (int jj = 0; jj < 8; ++jj)
                    acc[jj] += q * sm[QKV_OFF + (j0 + jj) * 91 + 30 + d];
            }
            const float scale = 1.0f / 5.477225575051661f;
            #pragma unroll
            for (int jj = 0; jj < 8; ++jj)
                sm[SC_OFF + lane_i * 65 + j0 + jj] = acc[jj] * scale;
        }
        __syncthreads();

        // softmax rows: 8 lanes per row
        {
            const int row = tid >> 3, ls = tid & 7;
            float v[8];
            #pragma unroll
            for (int m = 0; m < 8; ++m) v[m] = sm[SC_OFF + row * 65 + ls + 8 * m];
            float mx = v[0];
            #pragma unroll
            for (int m = 1; m < 8; ++m) mx = fmaxf(mx, v[m]);
            mx = fmaxf(mx, __shfl_xor(mx, 1));
            mx = fmaxf(mx, __shfl_xor(mx, 2));
            mx = fmaxf(mx, __shfl_xor(mx, 4));
            float s = 0.f;
            #pragma unroll
            for (int m = 0; m < 8; ++m) { v[m] = expf(v[m] - mx); s += v[m]; }
            s += __shfl_xor(s, 1);
            s += __shfl_xor(s, 2);
            s += __shfl_xor(s, 4);
            float inv = 1.0f / s;
            #pragma unroll
            for (int m = 0; m < 8; ++m) sm[SC_OFF + row * 65 + ls + 8 * m] = v[m] * inv;
        }
        __syncthreads();

        // PV + sigmoid gate -> attn_all
        {
            const int dg = jg;
            float acc[4] = {0.f, 0.f, 0.f, 0.f};
            for (int j = 0; j < NK; ++j) {
                float p = sm[SC_OFF + lane_i * 65 + j];
                #pragma unroll
                for (int dd = 0; dd < 4; ++dd) {
                    int d = dg * 4 + dd;
                    if (d < HD) acc[dd] += p * sm[QKV_OFF + j * 91 + 60 + d];
                }
            }
            float g = vals_s[h * NK + lane_i];
            #pragma unroll
            for (int dd = 0; dd < 4; ++dd) {
                int d = dg * 4 + dd;
                if (d < HD) attn_all[(h * NK + lane_i) * 31 + d] = acc[dd] * g;
            }
        }
        __syncthreads();
    }

    // ---------------- phase B: Wo GEMM + scatter (two channel halves) -------
    for (int half = 0; half < 2; ++half) {
        for (int f = tid; f < NL * 91; f += 512) sm[REG_OFF + f] = 0.f;
        __syncthreads();
        for (int h = 0; h < NE; ++h) {
            const int j0 = jg * 12;
            float acc[12];
            #pragma unroll
            for (int jj = 0; jj < 12; ++jj) acc[jj] = 0.f;
            const float* wo = Wo + h * HD * NC + half * 90;
            for (int d = 0; d < HD; ++d) {
                float a = attn_all[(h * NK + lane_i) * 31 + d];
                const float2* wo2 = (const float2*)(wo + d * NC + j0);
                #pragma unroll
                for (int jj = 0; jj < 6; ++jj) {
                    if (j0 + 2 * jj < 90) {
                        float2 wv = wo2[jj];
                        acc[2 * jj]     += a * wv.x;
                        acc[2 * jj + 1] += a * wv.y;
                    }
                }
            }
            const int tok = idx_s[h * NK + lane_i];
            // no race: same wave -> distinct tok; different wave -> distinct jg cols
            #pragma unroll
            for (int jj = 0; jj < 12; ++jj)
                if (j0 + jj < 90) sm[REG_OFF + tok * 91 + j0 + jj] += acc[jj];
        }
        __syncthreads();
        for (int f = tid; f < NL * 90; f += 512) {
            int t = f / 90, cc = f % 90;
            y[((long)w * NL + t) * NC + half * 90 + cc] = sm[REG_OFF + t * 91 + cc];
        }
        __syncthreads();
    }
}

// ---------------------------------------------------------------------------
// Kernel 3: out[p,o] = sum_c y[p,c]*Wp[o,c] + bp[o], window->BHWC layout
// grid 2048 x 512 threads, dynamic LDS (128 tokens staged per half)
// ---------------------------------------------------------------------------
__global__ __launch_bounds__(512) void k_proj(
    const float* __restrict__ y, const float* __restrict__ Wp,
    const float* __restrict__ bp, float* __restrict__ out)
{
    extern __shared__ float ys[];  // 128 * 181
    const int w   = blockIdx.x;
    const int tid = threadIdx.x;
    const int b = w >> 8, hb = (w >> 4) & 15, wb = w & 15;
    const int t_l = tid & 127;
    const int jg  = tid >> 7;      // 0..3, 45 output cols each, uniform per wave

    for (int half = 0; half < 2; ++half) {
        for (int f = tid; f < 128 * NC; f += 512) {
            int t = f / NC, c = f % NC;
            ys[t * 181 + c] = y[((long)w * NL + half * 128 + t) * NC + c];
        }
        __syncthreads();

        const int tok = half * 128 + t_l;
        const int r = tok >> 4, cl = tok & 15;
        const long obase = (((long)b * NH + hb * 16 + r) * NW + wb * 16 + cl) * NC;

        for (int og = 0; og < 3; ++og) {
            const int o0 = jg * 45 + og * 15;
            float acc[15];
            #pragma unroll
            for (int oo = 0; oo < 15; ++oo) acc[oo] = 0.f;
            for (int c = 0; c < NC; c += 2) {
                float x0 = ys[t_l * 181 + c];
                float x1 = ys[t_l * 181 + c + 1];
                #pragma unroll
                for (int oo = 0; oo < 15; ++oo) {
                    float2 wv = *(const float2*)(Wp + (o0 + oo) * NC + c);
                    acc[oo] += x0 * wv.x + x1 * wv.y;
                }
            }
            #pragma unroll
            for (int oo = 0; oo < 15; ++oo)
                out[obase + o0 + oo] = acc[oo] + bp[o0 + oo];
        }
        __syncthreads();
    }
}

// ---------------------------------------------------------------------------
extern "C" void kernel_launch(void* const* d_in, const int* in_sizes, int n_in,
                              void* d_out, int out_size, void* d_ws, size_t ws_size,
                              hipStream_t stream) {
    const float* x    = (const float*)d_in[0];
    const float* Wr   = (const float*)d_in[1];
    const float* Wqkv = (const float*)d_in[2];
    const float* Wo   = (const float*)d_in[3];
    const float* Wp   = (const float*)d_in[4];
    const float* bp   = (const float*)d_in[5];
    float* out = (float*)d_out;

    // workspace layout: idx (3.0 MB) | vals (3.0 MB) | y (360 MB)
    char* ws = (char*)d_ws;
    int*   idx_g  = (int*)ws;
    float* vals_g = (float*)(ws + (size_t)NWIN * NE * NK * 4);
    float* y      = (float*)(ws + 2 * (size_t)NWIN * NE * NK * 4);

    k_router_topk<<<NWIN, 256, 0, stream>>>(x, Wr, idx_g, vals_g);
    k_attn<<<NWIN, 512, K2_LDS_FLOATS * 4, stream>>>(x, Wqkv, Wo, idx_g, vals_g, y);
    k_proj<<<NWIN, 512, 128 * 181 * 4, stream>>>(y, Wp, bp, out);
}

// Round 2
// 945.101 us; speedup vs baseline: 11.5762x; 11.5762x over previous
//
#include <hip/hip_runtime.h>
#include <math.h>

#define NB 8
#define NH 256
#define NW 256
#define NC 180
#define NE 6
#define HD 30
#define NL 256
#define NK 64
#define NWIN 2048

typedef __attribute__((ext_vector_type(8))) short bf16x8;
typedef __attribute__((ext_vector_type(4))) float f32x4;

union FU { bf16x8 f; uint2 u2[2]; unsigned short s[8]; };

static __device__ __forceinline__ unsigned short f2bf(float x) {
    unsigned u = __float_as_uint(x);
    unsigned r = (u + 0x7FFFu + ((u >> 16) & 1u)) >> 16;
    return (unsigned short)r;
}
static __device__ __forceinline__ float bf2f(unsigned short h) {
    return __uint_as_float(((unsigned)h) << 16);
}
static __device__ __forceinline__ bf16x8 ld8(const unsigned short* p) {
    FU t;
    t.u2[0] = *(const uint2*)p;
    t.u2[1] = *(const uint2*)(p + 16);
    return t.f;
}

// ---------------------------------------------------------------------------
// prep: transpose+pad weights to bf16
//  Wqkv_t[h][n<96][k<200] = Wqkv[h][k][n]   (n>=90 or k>=180 -> 0)
//  Wo_t  [h][o<192][d<40] = Wo[h][d][o]     (o>=180 or d>=30 -> 0)
//  Wp_b  [o<192][c<200]   = Wp[o][c]        (o>=180 or c>=180 -> 0)
// ---------------------------------------------------------------------------
__global__ __launch_bounds__(256) void k_prep(
    const float* __restrict__ Wqkv, const float* __restrict__ Wo,
    const float* __restrict__ Wp,
    unsigned short* __restrict__ Wqkv_t, unsigned short* __restrict__ Wo_t,
    unsigned short* __restrict__ Wp_b)
{
    int i = blockIdx.x * 256 + threadIdx.x;
    if (i < NE * 96 * 200) {
        int h = i / (96 * 200), rm = i % (96 * 200), n = rm / 200, k = rm % 200;
        float v = (n < 90 && k < 180) ? Wqkv[((long)h * 180 + k) * 90 + n] : 0.f;
        Wqkv_t[i] = f2bf(v);
    }
    if (i < NE * 192 * 40) {
        int h = i / (192 * 40), rm = i % (192 * 40), o = rm / 40, d = rm % 40;
        float v = (o < 180 && d < 30) ? Wo[((long)h * 30 + d) * 180 + o] : 0.f;
        Wo_t[i] = f2bf(v);
    }
    if (i < 192 * 200) {
        int o = i / 200, c = i % 200;
        float v = (o < 180 && c < 180) ? Wp[o * 180 + c] : 0.f;
        Wp_b[i] = f2bf(v);
    }
}

// ---------------------------------------------------------------------------
// Kernel 1: router + top-64 (unchanged from round 1)
// ---------------------------------------------------------------------------
__global__ __launch_bounds__(256) void k_router_topk(
    const float* __restrict__ x, const float* __restrict__ Wr,
    int* __restrict__ idx_g, float* __restrict__ vals_g)
{
    __shared__ float wr_s[NE * NC];
    __shared__ float xs[32 * 181];
    __shared__ float lg[NE * NL];

    const int w   = blockIdx.x;
    const int tid = threadIdx.x;
    const int b = w >> 8, hb = (w >> 4) & 15, wb = w & 15;
    const long win_base = (((long)b * NH + hb * 16) * NW + wb * 16) * NC;

    for (int f = tid; f < NE * NC; f += 256) wr_s[f] = Wr[f];
    __syncthreads();

    for (int tile = 0; tile < 8; ++tile) {
        for (int f = tid; f < 32 * NC; f += 256) {
            int tl = f / NC, ch = f % NC;
            int tok = tile * 32 + tl;
            int r = tok >> 4, cl = tok & 15;
            xs[tl * 181 + ch] = x[win_base + ((long)r * NW + cl) * NC + ch];
        }
        __syncthreads();
        if (tid < 192) {
            int tl = tid & 31, e = tid >> 5;
            float acc = 0.f;
            for (int c = 0; c < NC; ++c) acc += xs[tl * 181 + c] * wr_s[e * NC + c];
            lg[e * NL + tile * 32 + tl] = 1.0f / (1.0f + expf(-acc));
        }
        __syncthreads();
    }

    for (int e = 0; e < NE; ++e) {
        float vt = lg[e * NL + tid];
        if (tid == 0) {
            idx_g[(w * NE + e) * NK]  = 0;
            vals_g[(w * NE + e) * NK] = vt;
        } else {
            int rank = 0;
            for (int j = 1; j < NL; ++j) {
                float vj = lg[e * NL + j];
                rank += (vj > vt) || (vj == vt && j < tid);
            }
            if (rank < NK - 1) {
                idx_g[(w * NE + e) * NK + 1 + rank]  = tid;
                vals_g[(w * NE + e) * NK + 1 + rank] = vt;
            }
        }
    }
}

// ---------------------------------------------------------------------------
// Kernel 2 (fused): per-window MFMA expert attention + scatter + out proj
// grid 2048 x 512, dynamic LDS 146688 B
// LDS map (bytes):
//   0      : y_s   [256][200] bf16 (102400)     persists whole kernel
//   102400 : R1 region (25600):
//              xg_s [64][200] bf16   (gather, dead after QKV)
//              sc_s [64][68] f32 (17408) | at_s [64][40] bf16 at +17408 (5120)
//              p_s  [64][72] bf16 (9216, overlays sc after barrier)
//   128000 : q_s  [64][40] bf16 (5120)
//   133120 : k_s  [64][40] bf16 (5120)
//   138240 : vt_s [32][72] bf16 (4608)
//   142848 : idx_s 384 i32 | 144384: val_s 384 f32 | 145920: bp_s 192 f32
// ---------------------------------------------------------------------------
#define LDS_TOTAL 146688

__global__ __launch_bounds__(512) void k_fused(
    const float* __restrict__ x,
    const unsigned short* __restrict__ Wqkv_t,
    const unsigned short* __restrict__ Wo_t,
    const unsigned short* __restrict__ Wp_b,
    const float* __restrict__ bp,
    const int* __restrict__ idx_g, const float* __restrict__ vals_g,
    float* __restrict__ out)
{
    extern __shared__ char smraw[];
    unsigned short* y_s  = (unsigned short*)(smraw);
    unsigned short* xg_s = (unsigned short*)(smraw + 102400);
    float*          sc_s = (float*)(smraw + 102400);
    unsigned short* p_s  = (unsigned short*)(smraw + 102400);
    unsigned short* at_s = (unsigned short*)(smraw + 102400 + 17408);
    unsigned short* q_s  = (unsigned short*)(smraw + 128000);
    unsigned short* k_s  = (unsigned short*)(smraw + 133120);
    unsigned short* vt_s = (unsigned short*)(smraw + 138240);
    int*   idx_s = (int*)(smraw + 142848);
    float* val_s = (float*)(smraw + 144384);
    float* bp_s  = (float*)(smraw + 145920);

    const int w   = blockIdx.x;
    const int tid = threadIdx.x;
    const int b = w >> 8, hb = (w >> 4) & 15, wb = w & 15;
    const long win_base = (((long)b * NH + hb * 16) * NW + wb * 16) * NC;

    const int wv = tid >> 6;      // wave 0..7
    const int ln = tid & 63;
    const int lr = ln & 15;       // lane low (col of D / row of A / row of B)
    const int lg = ln >> 4;       // lane group (k-subgroup / D-row group)

    // ---- init: idx/vals/bias, zero y_s and pads ----
    for (int f = tid; f < NE * NK; f += 512) {
        idx_s[f] = idx_g[(long)w * NE * NK + f];
        val_s[f] = vals_g[(long)w * NE * NK + f];
    }
    for (int f = tid; f < 192; f += 512) bp_s[f] = (f < NC) ? bp[f] : 0.f;
    for (int f = tid; f < 6400; f += 512) ((uint4*)y_s)[f] = make_uint4(0, 0, 0, 0);
    for (int f = tid; f < 640; f += 512) {  // Q/K pad cols 30..39 = 0
        int row = f / 10, cc = f % 10;
        q_s[row * 40 + 30 + cc] = 0;
        k_s[row * 40 + 30 + cc] = 0;
    }
    for (int f = tid; f < 144; f += 512) vt_s[30 * 72 + f] = 0;  // Vt rows 30,31
    __syncthreads();

    // ==================== per-head attention ====================
    for (int h = 0; h < NE; ++h) {
        // ---- A1: gather 64 selected tokens -> xg_s bf16 [64][200] ----
        {
            int slot = tid >> 3, oct = tid & 7;
            int tok = idx_s[h * NK + slot];
            const float* src = x + win_base + (((long)(tok >> 4)) * NW + (tok & 15)) * NC;
            int c0 = oct * 24;
            unsigned v24[12];
            if (oct < 7) {
                #pragma unroll
                for (int i = 0; i < 6; ++i) {
                    float4 t = *(const float4*)(src + c0 + i * 4);
                    v24[i * 2]     = (unsigned)f2bf(t.x) | ((unsigned)f2bf(t.y) << 16);
                    v24[i * 2 + 1] = (unsigned)f2bf(t.z) | ((unsigned)f2bf(t.w) << 16);
                }
            } else {
                #pragma unroll
                for (int i = 0; i < 3; ++i) {
                    float4 t = *(const float4*)(src + c0 + i * 4);
                    v24[i * 2]     = (unsigned)f2bf(t.x) | ((unsigned)f2bf(t.y) << 16);
                    v24[i * 2 + 1] = (unsigned)f2bf(t.z) | ((unsigned)f2bf(t.w) << 16);
                }
                #pragma unroll
                for (int i = 6; i < 12; ++i) v24[i] = 0;
            }
            uint4* dst = (uint4*)(xg_s + slot * 200 + c0);
            dst[0] = make_uint4(v24[0], v24[1], v24[2], v24[3]);
            dst[1] = make_uint4(v24[4], v24[5], v24[6], v24[7]);
            dst[2] = make_uint4(v24[8], v24[9], v24[10], v24[11]);
        }
        __syncthreads();

        // ---- A2: QKV = Xg @ Wqkv  (M=64,N=96,K=192) ----
        {
            const int mt = wv >> 1, nh2 = wv & 1;
            bf16x8 A[6];
            const unsigned short* arow = xg_s + (16 * mt + lr) * 200 + 4 * lg;
            #pragma unroll
            for (int kt = 0; kt < 6; ++kt) A[kt] = ld8(arow + 32 * kt);
            #pragma unroll
            for (int i = 0; i < 3; ++i) {
                int nt = nh2 * 3 + i;
                const unsigned short* brow =
                    Wqkv_t + ((long)h * 96 + 16 * nt + lr) * 200 + 4 * lg;
                f32x4 acc = {0.f, 0.f, 0.f, 0.f};
                #pragma unroll
                for (int kt = 0; kt < 6; ++kt)
                    acc = __builtin_amdgcn_mfma_f32_16x16x32_bf16(A[kt], ld8(brow + 32 * kt), acc, 0, 0, 0);
                int cg = 16 * nt + lr;       // qkv column
                int r0 = 16 * mt + 4 * lg;   // token row base
                if (cg < 30) {
                    #pragma unroll
                    for (int r = 0; r < 4; ++r) q_s[(r0 + r) * 40 + cg] = f2bf(acc[r]);
                } else if (cg < 60) {
                    #pragma unroll
                    for (int r = 0; r < 4; ++r) k_s[(r0 + r) * 40 + (cg - 30)] = f2bf(acc[r]);
                } else if (cg < 90) {
                    int d = cg - 60;
                    unsigned lo = (unsigned)f2bf(acc[0]) | ((unsigned)f2bf(acc[1]) << 16);
                    unsigned hi = (unsigned)f2bf(acc[2]) | ((unsigned)f2bf(acc[3]) << 16);
                    *(uint2*)(vt_s + d * 72 + r0) = make_uint2(lo, hi);
                }
            }
        }
        __syncthreads();

        // ---- A3: scores = Q K^T / sqrt(30)  (M=64,N=64,K=32) ----
        {
            const int qt = wv >> 1;
            const unsigned short* qrow = q_s + (16 * qt + lr) * 40 + 4 * lg;
            bf16x8 a = ld8(qrow);
            #pragma unroll
            for (int i = 0; i < 2; ++i) {
                int kt = (wv & 1) * 2 + i;
                const unsigned short* krow = k_s + (16 * kt + lr) * 40 + 4 * lg;
                f32x4 acc = {0.f, 0.f, 0.f, 0.f};
                acc = __builtin_amdgcn_mfma_f32_16x16x32_bf16(a, ld8(krow), acc, 0, 0, 0);
                int r0 = 16 * qt + 4 * lg, cg = 16 * kt + lr;
                #pragma unroll
                for (int r = 0; r < 4; ++r)
                    sc_s[(r0 + r) * 68 + cg] = acc[r] * 0.18257418583505536f;
            }
        }
        __syncthreads();

        // ---- A4: softmax rows (8 lanes/row) + gate, write P bf16 ----
        {
            const int row = tid >> 3, ls = tid & 7;
            float v[8];
            #pragma unroll
            for (int m = 0; m < 8; ++m) v[m] = sc_s[row * 68 + ls + 8 * m];
            float mx = v[0];
            #pragma unroll
            for (int m = 1; m < 8; ++m) mx = fmaxf(mx, v[m]);
            mx = fmaxf(mx, __shfl_xor(mx, 1));
            mx = fmaxf(mx, __shfl_xor(mx, 2));
            mx = fmaxf(mx, __shfl_xor(mx, 4));
            float s = 0.f;
            #pragma unroll
            for (int m = 0; m < 8; ++m) { v[m] = __expf(v[m] - mx); s += v[m]; }
            s += __shfl_xor(s, 1);
            s += __shfl_xor(s, 2);
            s += __shfl_xor(s, 4);
            float g = val_s[h * NK + row] / s;
            __syncthreads();   // sc reads done before P overlays sc
            #pragma unroll
            for (int m = 0; m < 8; ++m) p_s[row * 72 + ls + 8 * m] = f2bf(v[m] * g);
        }
        __syncthreads();

        // ---- A5: attn = P @ V  (M=64,N=32,K=64) ----
        {
            const int mt = wv >> 1, nt = wv & 1;
            const unsigned short* arow = p_s + (16 * mt + lr) * 72 + 4 * lg;
            const unsigned short* brow = vt_s + (16 * nt + lr) * 72 + 4 * lg;
            f32x4 acc = {0.f, 0.f, 0.f, 0.f};
            #pragma unroll
            for (int kt = 0; kt < 2; ++kt)
                acc = __builtin_amdgcn_mfma_f32_16x16x32_bf16(ld8(arow + 32 * kt), ld8(brow + 32 * kt), acc, 0, 0, 0);
            int r0 = 16 * mt + 4 * lg, d = 16 * nt + lr;
            #pragma unroll
            for (int r = 0; r < 4; ++r) at_s[(r0 + r) * 40 + d] = f2bf(acc[r]);
        }
        __syncthreads();

        // ---- A6: pre = attn @ Wo, scatter-add into y_s ----
        {
            const int mt = wv >> 1, nh2 = wv & 1;
            const unsigned short* arow = at_s + (16 * mt + lr) * 40 + 4 * lg;
            bf16x8 a = ld8(arow);
            int r0 = 16 * mt + 4 * lg;
            int tokr[4];
            #pragma unroll
            for (int r = 0; r < 4; ++r) tokr[r] = idx_s[h * NK + r0 + r];
            #pragma unroll
            for (int i = 0; i < 6; ++i) {
                int nt = nh2 * 6 + i;
                const unsigned short* brow =
                    Wo_t + ((long)h * 192 + 16 * nt + lr) * 40 + 4 * lg;
                f32x4 acc = {0.f, 0.f, 0.f, 0.f};
                acc = __builtin_amdgcn_mfma_f32_16x16x32_bf16(a, ld8(brow), acc, 0, 0, 0);
                int o = 16 * nt + lr;
                if (o < NC) {
                    float cur[4];
                    #pragma unroll
                    for (int r = 0; r < 4; ++r) cur[r] = bf2f(y_s[tokr[r] * 200 + o]);
                    #pragma unroll
                    for (int r = 0; r < 4; ++r) y_s[tokr[r] * 200 + o] = f2bf(cur[r] + acc[r]);
                }
            }
        }
        __syncthreads();
    }

    // ==================== phase C: out = y @ Wp^T + bp ====================
    {
        f32x4 acc[2][12];
        #pragma unroll
        for (int m = 0; m < 2; ++m)
            #pragma unroll
            for (int nt = 0; nt < 12; ++nt) acc[m][nt] = (f32x4){0.f, 0.f, 0.f, 0.f};

        #pragma unroll
        for (int kt = 0; kt < 6; ++kt) {
            const unsigned short* a0 = y_s + (32 * wv + lr) * 200 + 4 * lg + 32 * kt;
            bf16x8 A0 = ld8(a0);
            bf16x8 A1 = ld8(a0 + 16 * 200);
            const unsigned short* bbase = Wp_b + (long)lr * 200 + 4 * lg + 32 * kt;
            #pragma unroll
            for (int nt = 0; nt < 12; ++nt) {
                bf16x8 bfr = ld8(bbase + (long)16 * nt * 200);
                acc[0][nt] = __builtin_amdgcn_mfma_f32_16x16x32_bf16(A0, bfr, acc[0][nt], 0, 0, 0);
                acc[1][nt] = __builtin_amdgcn_mfma_f32_16x16x32_bf16(A1, bfr, acc[1][nt], 0, 0, 0);
            }
        }
        #pragma unroll
        for (int nt = 0; nt < 12; ++nt) {
            int o = 16 * nt + lr;
            if (o >= NC) continue;
            float bias = bp_s[o];
            #pragma unroll
            for (int m = 0; m < 2; ++m) {
                int r0 = 16 * (2 * wv + m) + 4 * lg;
                #pragma unroll
                for (int r = 0; r < 4; ++r) {
                    int tok = r0 + r;
                    long addr = (((long)b * NH + hb * 16 + (tok >> 4)) * NW + wb * 16 + (tok & 15)) * NC + o;
                    out[addr] = acc[m][nt][r] + bias;
                }
            }
        }
    }
}

// ---------------------------------------------------------------------------
extern "C" void kernel_launch(void* const* d_in, const int* in_sizes, int n_in,
                              void* d_out, int out_size, void* d_ws, size_t ws_size,
                              hipStream_t stream) {
    const float* x    = (const float*)d_in[0];
    const float* Wr   = (const float*)d_in[1];
    const float* Wqkv = (const float*)d_in[2];
    const float* Wo   = (const float*)d_in[3];
    const float* Wp   = (const float*)d_in[4];
    const float* bp   = (const float*)d_in[5];
    float* out = (float*)d_out;

    char* ws = (char*)d_ws;
    int*   idx_g  = (int*)ws;                                   // 3 MB
    float* vals_g = (float*)(ws + (size_t)NWIN * NE * NK * 4);  // 3 MB
    size_t off = 2 * (size_t)NWIN * NE * NK * 4;
    unsigned short* Wqkv_t = (unsigned short*)(ws + off);       // 230400 B
    off += (size_t)NE * 96 * 200 * 2;
    unsigned short* Wo_t = (unsigned short*)(ws + off);         // 92160 B
    off += (size_t)NE * 192 * 40 * 2;
    unsigned short* Wp_b = (unsigned short*)(ws + off);         // 76800 B

    k_prep<<<450, 256, 0, stream>>>(Wqkv, Wo, Wp, Wqkv_t, Wo_t, Wp_b);
    k_router_topk<<<NWIN, 256, 0, stream>>>(x, Wr, idx_g, vals_g);
    k_fused<<<NWIN, 512, LDS_TOTAL, stream>>>(x, Wqkv_t, Wo_t, Wp_b, bp,
                                              idx_g, vals_g, out);
}

// Round 6
// 868.448 us; speedup vs baseline: 12.5980x; 1.0883x over previous
//
#include <hip/hip_runtime.h>
#include <math.h>

#define NB 8
#define NH 256
#define NW 256
#define NC 180
#define NE 6
#define HD 30
#define NL 256
#define NK 64
#define NWIN 2048

typedef __attribute__((ext_vector_type(8))) short bf16x8;
typedef __attribute__((ext_vector_type(4))) float f32x4;

union FU { bf16x8 f; unsigned u[4]; unsigned short s[8]; };

static __device__ __forceinline__ unsigned short f2bf(float x) {
    unsigned u = __float_as_uint(x);
    unsigned r = (u + 0x7FFFu + ((u >> 16) & 1u)) >> 16;
    return (unsigned short)r;
}
static __device__ __forceinline__ unsigned pk2(float a, float b) {
    return (unsigned)f2bf(a) | ((unsigned)f2bf(b) << 16);
}
static __device__ __forceinline__ float bf2f(unsigned short h) {
    return __uint_as_float(((unsigned)h) << 16);
}
// fragment load: elements {p[0..3], p[16..19]} — 8B-aligned rows
static __device__ __forceinline__ bf16x8 ld8(const unsigned short* p) {
    FU t;
    *(uint2*)&t.u[0] = *(const uint2*)p;
    *(uint2*)&t.u[2] = *(const uint2*)(p + 16);
    return t.f;
}
// same element order, 4B-aligned rows (stride-34 LDS)
static __device__ __forceinline__ bf16x8 ld8q(const unsigned short* p) {
    FU t;
    t.u[0] = *(const unsigned*)p;
    t.u[1] = *(const unsigned*)(p + 2);
    t.u[2] = *(const unsigned*)(p + 16);
    t.u[3] = *(const unsigned*)(p + 18);
    return t.f;
}
static __device__ __forceinline__ bf16x8 pack8(float4 a, float4 b) {
    FU t;
    t.u[0] = pk2(a.x, a.y); t.u[1] = pk2(a.z, a.w);
    t.u[2] = pk2(b.x, b.y); t.u[3] = pk2(b.z, b.w);
    return t.f;
}

// ---------------------------------------------------------------------------
// prep: Wqkv_t[h][n'<96][k<192] (n' = sec*32+r, n = sec*30+r; pads zero)
//       Wcomb_t[h][o<192][d<32] = (Wo[h] @ Wp^T)^T  (pads zero)
// ---------------------------------------------------------------------------
__global__ __launch_bounds__(256) void k_prep(
    const float* __restrict__ Wqkv, const float* __restrict__ Wo,
    const float* __restrict__ Wp,
    unsigned short* __restrict__ Wqkv_t, unsigned short* __restrict__ Wcomb_t)
{
    int i = blockIdx.x * 256 + threadIdx.x;
    if (i < NE * 96 * 192) {
        int h = i / (96 * 192), rm = i % (96 * 192), np = rm / 192, k = rm % 192;
        int sec = np >> 5, r = np & 31;
        float v = (r < 30 && k < NC) ? Wqkv[((long)h * NC + k) * 90 + sec * 30 + r] : 0.f;
        Wqkv_t[i] = f2bf(v);
    }
    if (i < NE * 192 * 32) {
        int h = i / (192 * 32), rm = i % (192 * 32), o = rm / 32, d = rm & 31;
        float acc = 0.f;
        if (o < NC && d < HD) {
            const float* wo = Wo + ((long)h * HD + d) * NC;
            const float* wp = Wp + (long)o * NC;
            for (int c = 0; c < NC; ++c) acc += wo[c] * wp[c];
        }
        Wcomb_t[i] = f2bf(acc);
    }
}

// ---------------------------------------------------------------------------
// Router: VERBATIM round-1 kernel (passed at 2.4e-4 => its compiled logit &
// sigmoid bits match the np reference's selection exactly). Do not touch.
// ---------------------------------------------------------------------------
__global__ __launch_bounds__(256) void k_router_topk(
    const float* __restrict__ x, const float* __restrict__ Wr,
    int* __restrict__ idx_g, float* __restrict__ vals_g)
{
    __shared__ float wr_s[NE * NC];
    __shared__ float xs[32 * 181];
    __shared__ float lg[NE * NL];

    const int w   = blockIdx.x;
    const int tid = threadIdx.x;
    const int b = w >> 8, hb = (w >> 4) & 15, wb = w & 15;
    const long win_base = (((long)b * NH + hb * 16) * NW + wb * 16) * NC;

    for (int f = tid; f < NE * NC; f += 256) wr_s[f] = Wr[f];
    __syncthreads();

    for (int tile = 0; tile < 8; ++tile) {
        for (int f = tid; f < 32 * NC; f += 256) {
            int tl = f / NC, ch = f % NC;
            int tok = tile * 32 + tl;
            int r = tok >> 4, cl = tok & 15;
            xs[tl * 181 + ch] = x[win_base + ((long)r * NW + cl) * NC + ch];
        }
        __syncthreads();
        if (tid < 192) {
            int tl = tid & 31, e = tid >> 5;
            float acc = 0.f;
            for (int c = 0; c < NC; ++c) acc += xs[tl * 181 + c] * wr_s[e * NC + c];
            lg[e * NL + tile * 32 + tl] = 1.0f / (1.0f + expf(-acc));
        }
        __syncthreads();
    }

    for (int e = 0; e < NE; ++e) {
        float vt = lg[e * NL + tid];
        if (tid == 0) {
            idx_g[(w * NE + e) * NK]  = 0;
            vals_g[(w * NE + e) * NK] = vt;
        } else {
            int rank = 0;
            for (int j = 1; j < NL; ++j) {
                float vj = lg[e * NL + j];
                rank += (vj > vt) || (vj == vt && j < tid);
            }
            if (rank < NK - 1) {
                idx_g[(w * NE + e) * NK + 1 + rank]  = tid;
                vals_g[(w * NE + e) * NK + 1 + rank] = vt;
            }
        }
    }
}

// ---------------------------------------------------------------------------
// fused: per-head attention (wave=head, in-register softmax)
//        -> comb GEMM + fp32 LDS scatter -> out + bias
// LDS (bytes): 0: q/k per head (h*8704; q 4352 + k 4352, stride 34 u16)
//                 [overlay phase B: outf f32[256][48] = 49152]
//              52224: at_s[h] = +h*4608 (u16 [64][36])
//              79872: idx u8[384]; 80256: val f32[384]; total 81792
// ---------------------------------------------------------------------------
#define QK_BASE 0
#define AT_BASE 52224
#define IDX_BASE 79872
#define VAL_BASE 80256
#define LDS_TOTAL 81792

__global__ __launch_bounds__(384, 3) void k_fused(
    const float* __restrict__ x,
    const unsigned short* __restrict__ Wqkv_t,
    const unsigned short* __restrict__ Wcomb_t,
    const float* __restrict__ bp,
    const int* __restrict__ idx_g, const float* __restrict__ vals_g,
    float* __restrict__ out)
{
    extern __shared__ char sm[];
    const int w = blockIdx.x;
    const int tid = threadIdx.x;
    const int b = w >> 8, hb = (w >> 4) & 15, wb = w & 15;
    const long win_base = (((long)b * NH + hb * 16) * NW + wb * 16) * NC;

    const int wv = tid >> 6;
    const int ln = tid & 63;
    const int lr = ln & 15;
    const int lg = ln >> 4;

    unsigned char* idx_s = (unsigned char*)(sm + IDX_BASE);
    float* val_s = (float*)(sm + VAL_BASE);

    // ---- zero ALL LDS (defensive: no garbage reads anywhere) ----
    for (int f = tid; f < LDS_TOTAL / 4; f += 384) ((unsigned*)sm)[f] = 0u;
    __syncthreads();

    // ---- load selection from the verbatim-router's output ----
    for (int f = tid; f < NE * NK; f += 384) {
        idx_s[f] = (unsigned char)idx_g[(long)w * NE * NK + f];
        val_s[f] = vals_g[(long)w * NE * NK + f];
    }
    __syncthreads();

    // ================= Phase A: attention, wave = head =======================
    {
        const int h = wv;
        unsigned short* q_s = (unsigned short*)(sm + QK_BASE + h * 8704);
        unsigned short* k_s = q_s + 2176;
        unsigned short* at_s = (unsigned short*)(sm + AT_BASE + h * 4608);

        // --- QKV = gather(x) @ Wqkv_t : M=64, N=96, K=192 ---
        bf16x8 A[4][6];
        #pragma unroll
        for (int mt = 0; mt < 4; ++mt) {
            int tok = idx_s[h * NK + 16 * mt + lr];
            const float* xr = x + win_base + ((long)(tok >> 4) * NW + (tok & 15)) * NC;
            int c0 = 4 * lg;
            #pragma unroll
            for (int kt = 0; kt < 5; ++kt) {
                float4 a = *(const float4*)(xr + c0 + 32 * kt);
                float4 bb = *(const float4*)(xr + c0 + 32 * kt + 16);
                A[mt][kt] = pack8(a, bb);
            }
            {
                float4 a = *(const float4*)(xr + c0 + 160);
                float4 bb = make_float4(0.f, 0.f, 0.f, 0.f);
                if (lg == 0) bb = *(const float4*)(xr + 176);
                A[mt][5] = pack8(a, bb);
            }
        }
        unsigned V32[4][2][2];
        #pragma unroll
        for (int nt = 0; nt < 6; ++nt) {
            f32x4 acc[4];
            #pragma unroll
            for (int mt = 0; mt < 4; ++mt) acc[mt] = (f32x4){0.f, 0.f, 0.f, 0.f};
            const unsigned short* bbase = Wqkv_t + ((long)h * 96 + 16 * nt + lr) * 192 + 4 * lg;
            #pragma unroll
            for (int kt = 0; kt < 6; ++kt) {
                bf16x8 B = ld8(bbase + 32 * kt);
                #pragma unroll
                for (int mt = 0; mt < 4; ++mt)
                    acc[mt] = __builtin_amdgcn_mfma_f32_16x16x32_bf16(A[mt][kt], B, acc[mt], 0, 0, 0);
            }
            if (nt < 4) {
                unsigned short* dst = (nt < 2 ? q_s : k_s) + 16 * (nt & 1) + lr;
                #pragma unroll
                for (int mt = 0; mt < 4; ++mt) {
                    int row = 16 * mt + 4 * lg;
                    dst[(row + 0) * 34] = f2bf(acc[mt][0]);
                    dst[(row + 1) * 34] = f2bf(acc[mt][1]);
                    dst[(row + 2) * 34] = f2bf(acc[mt][2]);
                    dst[(row + 3) * 34] = f2bf(acc[mt][3]);
                }
            } else {
                #pragma unroll
                for (int mt = 0; mt < 4; ++mt) {
                    V32[mt][nt - 4][0] = pk2(acc[mt][0], acc[mt][1]);
                    V32[mt][nt - 4][1] = pk2(acc[mt][2], acc[mt][3]);
                }
            }
        }

        // --- scores^T = mfma(K, Q): lane holds col q=16nt+lr, rows k ---
        f32x4 s[4][4];
        {
            bf16x8 Bq[4];
            #pragma unroll
            for (int nt = 0; nt < 4; ++nt)
                Bq[nt] = ld8q(q_s + (16 * nt + lr) * 34 + 4 * lg);
            #pragma unroll
            for (int amt = 0; amt < 4; ++amt) {
                bf16x8 Ak = ld8q(k_s + (16 * amt + lr) * 34 + 4 * lg);
                #pragma unroll
                for (int nt = 0; nt < 4; ++nt)
                    s[amt][nt] = __builtin_amdgcn_mfma_f32_16x16x32_bf16(
                        Ak, Bq[nt], (f32x4){0.f, 0.f, 0.f, 0.f}, 0, 0, 0);
            }
        }

        // --- in-register softmax over k (rows) per q-column + gate ---
        float gsc[4];
        #pragma unroll
        for (int nt = 0; nt < 4; ++nt) {
            float mx = -1e30f;
            #pragma unroll
            for (int amt = 0; amt < 4; ++amt)
                #pragma unroll
                for (int r = 0; r < 4; ++r) mx = fmaxf(mx, s[amt][nt][r]);
            mx = fmaxf(mx, __shfl_xor(mx, 16));
            mx = fmaxf(mx, __shfl_xor(mx, 32));
            float sum = 0.f;
            #pragma unroll
            for (int amt = 0; amt < 4; ++amt)
                #pragma unroll
                for (int r = 0; r < 4; ++r) {
                    float p = __expf((s[amt][nt][r] - mx) * 0.18257418583505536f);
                    s[amt][nt][r] = p;
                    sum += p;
                }
            sum += __shfl_xor(sum, 16);
            sum += __shfl_xor(sum, 32);
            gsc[nt] = val_s[h * NK + 16 * nt + lr] / sum;
        }

        // --- attn^T = mfma(V^T, P^T): both operands packed in-lane ---
        f32x4 av[2][4];
        {
            bf16x8 Av[2][2];
            #pragma unroll
            for (int amt = 0; amt < 2; ++amt)
                #pragma unroll
                for (int kt = 0; kt < 2; ++kt) {
                    FU t;
                    t.u[0] = V32[2 * kt][amt][0];
                    t.u[1] = V32[2 * kt][amt][1];
                    t.u[2] = V32[2 * kt + 1][amt][0];
                    t.u[3] = V32[2 * kt + 1][amt][1];
                    Av[amt][kt] = t.f;
                }
            #pragma unroll
            for (int nt = 0; nt < 4; ++nt) {
                bf16x8 Pb[2];
                float g = gsc[nt];
                #pragma unroll
                for (int kt = 0; kt < 2; ++kt) {
                    FU t;
                    t.u[0] = pk2(s[2 * kt][nt][0] * g, s[2 * kt][nt][1] * g);
                    t.u[1] = pk2(s[2 * kt][nt][2] * g, s[2 * kt][nt][3] * g);
                    t.u[2] = pk2(s[2 * kt + 1][nt][0] * g, s[2 * kt + 1][nt][1] * g);
                    t.u[3] = pk2(s[2 * kt + 1][nt][2] * g, s[2 * kt + 1][nt][3] * g);
                    Pb[kt] = t.f;
                }
                #pragma unroll
                for (int amt = 0; amt < 2; ++amt) {
                    f32x4 a = (f32x4){0.f, 0.f, 0.f, 0.f};
                    a = __builtin_amdgcn_mfma_f32_16x16x32_bf16(Av[amt][0], Pb[0], a, 0, 0, 0);
                    a = __builtin_amdgcn_mfma_f32_16x16x32_bf16(Av[amt][1], Pb[1], a, 0, 0, 0);
                    av[amt][nt] = a;
                }
            }
        }
        // --- store attn to at_s[slot][d] (B-fragment-ready) ---
        unsigned* atw = (unsigned*)at_s;
        #pragma unroll
        for (int nt = 0; nt < 4; ++nt) {
            int base = (16 * nt + lr) * 18 + 2 * lg;
            #pragma unroll
            for (int amt = 0; amt < 2; ++amt) {
                atw[base + 8 * amt]     = pk2(av[amt][nt][0], av[amt][nt][1]);
                atw[base + 8 * amt + 1] = pk2(av[amt][nt][2], av[amt][nt][3]);
            }
        }
    }
    __syncthreads();

    // ====== Phase B: pre = attn @ Wcomb, fp32 LDS scatter, 4 passes =========
    float* outf = (float*)(sm + QK_BASE);  // [256][48] f32 = 49152 B
    for (int p = 0; p < 4; ++p) {
        for (int f = tid; f < 256 * 48; f += 384) outf[f] = 0.f;
        __syncthreads();
        if ((wv / 3) == (p & 1)) {
            const int wcol = wv % 3;
            #pragma unroll 1
            for (int h = 0; h < NE; ++h) {
                const unsigned short* at_h = (const unsigned short*)(sm + AT_BASE + h * 4608);
                bf16x8 Aw = ld8(Wcomb_t + ((long)h * 192 + p * 48 + 16 * wcol + lr) * 32 + 4 * lg);
                #pragma unroll
                for (int nt = 0; nt < 4; ++nt) {
                    bf16x8 Bt = ld8(at_h + (16 * nt + lr) * 36 + 4 * lg);
                    f32x4 acc = __builtin_amdgcn_mfma_f32_16x16x32_bf16(
                        Aw, Bt, (f32x4){0.f, 0.f, 0.f, 0.f}, 0, 0, 0);
                    int tok = idx_s[h * NK + 16 * nt + lr];
                    // races: waves -> disjoint 16-col slices; same wave: same lg
                    // -> distinct toks, diff lg -> distinct cols. RMW safe.
                    float* dst = outf + tok * 48 + 16 * wcol + 4 * lg;
                    dst[0] += acc[0];
                    dst[1] += acc[1];
                    dst[2] += acc[2];
                    dst[3] += acc[3];
                }
            }
        }
        __syncthreads();
        const int cl2 = (p == 3) ? 18 : 24;  // float2 cols this pass (c<180)
        for (int f = tid; f < 256 * cl2; f += 384) {
            int t = f / cl2, j = f % cl2;
            int c = 48 * p + 2 * j;
            float2 o;
            o.x = outf[t * 48 + 2 * j]     + bp[c];
            o.y = outf[t * 48 + 2 * j + 1] + bp[c + 1];
            long obase = (((long)b * NH + hb * 16 + (t >> 4)) * NW + wb * 16 + (t & 15)) * NC + c;
            *(float2*)(out + obase) = o;
        }
        __syncthreads();
    }
}

// ---------------------------------------------------------------------------
extern "C" void kernel_launch(void* const* d_in, const int* in_sizes, int n_in,
                              void* d_out, int out_size, void* d_ws, size_t ws_size,
                              hipStream_t stream) {
    const float* x    = (const float*)d_in[0];
    const float* Wr   = (const float*)d_in[1];
    const float* Wqkv = (const float*)d_in[2];
    const float* Wo   = (const float*)d_in[3];
    const float* Wp   = (const float*)d_in[4];
    const float* bp   = (const float*)d_in[5];
    float* out = (float*)d_out;

    char* ws = (char*)d_ws;
    unsigned short* Wqkv_t  = (unsigned short*)ws;                  // 221184 B
    unsigned short* Wcomb_t = (unsigned short*)(ws + 221184);       // 73728 B
    int*   idx_g  = (int*)(ws + 294912);                            // 3 MB
    float* vals_g = (float*)(ws + 294912 + (size_t)NWIN * NE * NK * 4);

    k_prep<<<432, 256, 0, stream>>>(Wqkv, Wo, Wp, Wqkv_t, Wcomb_t);
    k_router_topk<<<NWIN, 256, 0, stream>>>(x, Wr, idx_g, vals_g);
    k_fused<<<NWIN, 384, LDS_TOTAL, stream>>>(x, Wqkv_t, Wcomb_t, bp,
                                              idx_g, vals_g, out);
}

// Round 8
// 847.424 us; speedup vs baseline: 12.9106x; 1.0248x over previous
//
#include <hip/hip_runtime.h>
#include <math.h>

#define NB 8
#define NH 256
#define NW 256
#define NC 180
#define NE 6
#define HD 30
#define NL 256
#define NK 64
#define NWIN 2048

typedef __attribute__((ext_vector_type(8))) short bf16x8;
typedef __attribute__((ext_vector_type(4))) float f32x4;

union FU { bf16x8 f; unsigned u[4]; unsigned short s[8]; };

static __device__ __forceinline__ unsigned short f2bf(float x) {
    unsigned u = __float_as_uint(x);
    unsigned r = (u + 0x7FFFu + ((u >> 16) & 1u)) >> 16;
    return (unsigned short)r;
}
static __device__ __forceinline__ unsigned pk2(float a, float b) {
    return (unsigned)f2bf(a) | ((unsigned)f2bf(b) << 16);
}
// fragment load: elements {p[0..3], p[16..19]} — 8B-aligned rows
static __device__ __forceinline__ bf16x8 ld8(const unsigned short* p) {
    FU t;
    *(uint2*)&t.u[0] = *(const uint2*)p;
    *(uint2*)&t.u[2] = *(const uint2*)(p + 16);
    return t.f;
}
// same element order, 4B-aligned rows (stride-34 LDS)
static __device__ __forceinline__ bf16x8 ld8q(const unsigned short* p) {
    FU t;
    t.u[0] = *(const unsigned*)p;
    t.u[1] = *(const unsigned*)(p + 2);
    t.u[2] = *(const unsigned*)(p + 16);
    t.u[3] = *(const unsigned*)(p + 18);
    return t.f;
}
static __device__ __forceinline__ bf16x8 pack8(float4 a, float4 b) {
    FU t;
    t.u[0] = pk2(a.x, a.y); t.u[1] = pk2(a.z, a.w);
    t.u[2] = pk2(b.x, b.y); t.u[3] = pk2(b.z, b.w);
    return t.f;
}

// ---------------------------------------------------------------------------
// prep: Wqkv_t[h][n'<96][k<192] (n' = sec*32+r, n = sec*30+r; pads zero)
//       Wcomb_t[h][o<192][d<32] = (Wo[h] @ Wp^T)^T  (pads zero)
// ---------------------------------------------------------------------------
__global__ __launch_bounds__(256) void k_prep(
    const float* __restrict__ Wqkv, const float* __restrict__ Wo,
    const float* __restrict__ Wp,
    unsigned short* __restrict__ Wqkv_t, unsigned short* __restrict__ Wcomb_t)
{
    int i = blockIdx.x * 256 + threadIdx.x;
    if (i < NE * 96 * 192) {
        int h = i / (96 * 192), rm = i % (96 * 192), np = rm / 192, k = rm % 192;
        int sec = np >> 5, r = np & 31;
        float v = (r < 30 && k < NC) ? Wqkv[((long)h * NC + k) * 90 + sec * 30 + r] : 0.f;
        Wqkv_t[i] = f2bf(v);
    }
    if (i < NE * 192 * 32) {
        int h = i / (192 * 32), rm = i % (192 * 32), o = rm / 32, d = rm & 31;
        float acc = 0.f;
        if (o < NC && d < HD) {
            const float* wo = Wo + ((long)h * HD + d) * NC;
            const float* wp = Wp + (long)o * NC;
            for (int c = 0; c < NC; ++c) acc += wo[c] * wp[c];
        }
        Wcomb_t[i] = f2bf(acc);
    }
}

// ---------------------------------------------------------------------------
// Router: VERBATIM round-1 kernel (passed at 2.4e-4 => its compiled logit &
// sigmoid bits match the np reference's selection exactly). Do not touch.
// ---------------------------------------------------------------------------
__global__ __launch_bounds__(256) void k_router_topk(
    const float* __restrict__ x, const float* __restrict__ Wr,
    int* __restrict__ idx_g, float* __restrict__ vals_g)
{
    __shared__ float wr_s[NE * NC];
    __shared__ float xs[32 * 181];
    __shared__ float lg[NE * NL];

    const int w   = blockIdx.x;
    const int tid = threadIdx.x;
    const int b = w >> 8, hb = (w >> 4) & 15, wb = w & 15;
    const long win_base = (((long)b * NH + hb * 16) * NW + wb * 16) * NC;

    for (int f = tid; f < NE * NC; f += 256) wr_s[f] = Wr[f];
    __syncthreads();

    for (int tile = 0; tile < 8; ++tile) {
        for (int f = tid; f < 32 * NC; f += 256) {
            int tl = f / NC, ch = f % NC;
            int tok = tile * 32 + tl;
            int r = tok >> 4, cl = tok & 15;
            xs[tl * 181 + ch] = x[win_base + ((long)r * NW + cl) * NC + ch];
        }
        __syncthreads();
        if (tid < 192) {
            int tl = tid & 31, e = tid >> 5;
            float acc = 0.f;
            for (int c = 0; c < NC; ++c) acc += xs[tl * 181 + c] * wr_s[e * NC + c];
            lg[e * NL + tile * 32 + tl] = 1.0f / (1.0f + expf(-acc));
        }
        __syncthreads();
    }

    for (int e = 0; e < NE; ++e) {
        float vt = lg[e * NL + tid];
        if (tid == 0) {
            idx_g[(w * NE + e) * NK]  = 0;
            vals_g[(w * NE + e) * NK] = vt;
        } else {
            int rank = 0;
            for (int j = 1; j < NL; ++j) {
                float vj = lg[e * NL + j];
                rank += (vj > vt) || (vj == vt && j < tid);
            }
            if (rank < NK - 1) {
                idx_g[(w * NE + e) * NK + 1 + rank]  = tid;
                vals_g[(w * NE + e) * NK + 1 + rank] = vt;
            }
        }
    }
}

// ---------------------------------------------------------------------------
// fused: per-head attention (wave=head, in-register softmax)
//        -> comb GEMM + fp32 LDS scatter -> out + bias
// LDS (bytes): 0: q/k per head (h*8704; q 4352 + k 4352, stride 34 u16)
//                 [overlay phase B: outf f32[256][49] = 50176]
//              52224: at_s[h] = +h*4608 (u16 [64][36])
//              79872: idx u8[384]; 80256: val f32[384]; total 81792
// ---------------------------------------------------------------------------
#define QK_BASE 0
#define AT_BASE 52224
#define IDX_BASE 79872
#define VAL_BASE 80256
#define LDS_TOTAL 81792

__global__ __launch_bounds__(384, 3) void k_fused(
    const float* __restrict__ x,
    const unsigned short* __restrict__ Wqkv_t,
    const unsigned short* __restrict__ Wcomb_t,
    const float* __restrict__ bp,
    const int* __restrict__ idx_g, const float* __restrict__ vals_g,
    float* __restrict__ out)
{
    extern __shared__ char sm[];
    const int w = blockIdx.x;
    const int tid = threadIdx.x;
    const int b = w >> 8, hb = (w >> 4) & 15, wb = w & 15;
    const long win_base = (((long)b * NH + hb * 16) * NW + wb * 16) * NC;

    const int wv = tid >> 6;
    const int ln = tid & 63;
    const int lr = ln & 15;
    const int lg = ln >> 4;

    unsigned char* idx_s = (unsigned char*)(sm + IDX_BASE);
    float* val_s = (float*)(sm + VAL_BASE);

    // ---- load selection from the verbatim-router's output ----
    for (int f = tid; f < NE * NK; f += 384) {
        idx_s[f] = (unsigned char)idx_g[(long)w * NE * NK + f];
        val_s[f] = vals_g[(long)w * NE * NK + f];
    }
    __syncthreads();

    // ================= Phase A: attention, wave = head =======================
    {
        const int h = wv;
        unsigned short* q_s = (unsigned short*)(sm + QK_BASE + h * 8704);
        unsigned short* k_s = q_s + 2176;
        unsigned short* at_s = (unsigned short*)(sm + AT_BASE + h * 4608);

        // --- QKV = gather(x) @ Wqkv_t : M=64, N=96, K=192 ---
        // kt-outer / nt-inner: only 4 transient A-frags live (16 VGPR) +
        // acc[6][4] (96 VGPR) -> no scratch spill (round-6 killer).
        const float* xr[4];
        #pragma unroll
        for (int mt = 0; mt < 4; ++mt) {
            int tok = idx_s[h * NK + 16 * mt + lr];
            xr[mt] = x + win_base + ((long)(tok >> 4) * NW + (tok & 15)) * NC;
        }
        f32x4 acc[6][4];
        #pragma unroll
        for (int nt = 0; nt < 6; ++nt)
            #pragma unroll
            for (int mt = 0; mt < 4; ++mt) acc[nt][mt] = (f32x4){0.f, 0.f, 0.f, 0.f};

        const unsigned short* bb = Wqkv_t + ((long)h * 96 + lr) * 192 + 4 * lg;
        #pragma unroll
        for (int kt = 0; kt < 6; ++kt) {
            bf16x8 Amt[4];
            #pragma unroll
            for (int mt = 0; mt < 4; ++mt) {
                if (kt < 5) {
                    float4 a  = *(const float4*)(xr[mt] + 4 * lg + 32 * kt);
                    float4 b2 = *(const float4*)(xr[mt] + 4 * lg + 32 * kt + 16);
                    Amt[mt] = pack8(a, b2);
                } else {
                    float4 a  = *(const float4*)(xr[mt] + 4 * lg + 160);
                    float4 b2 = make_float4(0.f, 0.f, 0.f, 0.f);
                    if (lg == 0) b2 = *(const float4*)(xr[mt] + 176);
                    Amt[mt] = pack8(a, b2);
                }
            }
            #pragma unroll
            for (int nt = 0; nt < 6; ++nt) {
                bf16x8 B = ld8(bb + nt * (16 * 192) + kt * 32);
                #pragma unroll
                for (int mt = 0; mt < 4; ++mt)
                    acc[nt][mt] = __builtin_amdgcn_mfma_f32_16x16x32_bf16(Amt[mt], B, acc[nt][mt], 0, 0, 0);
            }
        }

        // --- write Q/K (nt 0..3) to LDS transpose buffers ---
        #pragma unroll
        for (int nt = 0; nt < 4; ++nt) {
            unsigned short* dst = (nt < 2 ? q_s : k_s) + 16 * (nt & 1) + lr;
            #pragma unroll
            for (int mt = 0; mt < 4; ++mt) {
                int row = 16 * mt + 4 * lg;
                dst[(row + 0) * 34] = f2bf(acc[nt][mt][0]);
                dst[(row + 1) * 34] = f2bf(acc[nt][mt][1]);
                dst[(row + 2) * 34] = f2bf(acc[nt][mt][2]);
                dst[(row + 3) * 34] = f2bf(acc[nt][mt][3]);
            }
        }
        // --- keep V (nt 4,5) in registers ---
        unsigned V32[4][2][2];
        #pragma unroll
        for (int j = 0; j < 2; ++j)
            #pragma unroll
            for (int mt = 0; mt < 4; ++mt) {
                V32[mt][j][0] = pk2(acc[4 + j][mt][0], acc[4 + j][mt][1]);
                V32[mt][j][1] = pk2(acc[4 + j][mt][2], acc[4 + j][mt][3]);
            }

        // BARRIER: the u16 ds_writes above and the u32 ds_reads below are
        // "no-alias" under TBAA, so without a barrier the compiler may hoist
        // the reads above the writes (round-7 NaN). __syncthreads() pins the
        // order (and costs ~nothing once per kernel).
        __syncthreads();

        // --- scores^T = mfma(K, Q): lane holds col q=16nt+lr, rows k ---
        f32x4 s[4][4];
        {
            bf16x8 Bq[4];
            #pragma unroll
            for (int nt = 0; nt < 4; ++nt)
                Bq[nt] = ld8q(q_s + (16 * nt + lr) * 34 + 4 * lg);
            #pragma unroll
            for (int amt = 0; amt < 4; ++amt) {
                bf16x8 Ak = ld8q(k_s + (16 * amt + lr) * 34 + 4 * lg);
                #pragma unroll
                for (int nt = 0; nt < 4; ++nt)
                    s[amt][nt] = __builtin_amdgcn_mfma_f32_16x16x32_bf16(
                        Ak, Bq[nt], (f32x4){0.f, 0.f, 0.f, 0.f}, 0, 0, 0);
            }
        }

        // --- in-register softmax over k (rows) per q-column + gate ---
        float gsc[4];
        #pragma unroll
        for (int nt = 0; nt < 4; ++nt) {
            float mx = -1e30f;
            #pragma unroll
            for (int amt = 0; amt < 4; ++amt)
                #pragma unroll
                for (int r = 0; r < 4; ++r) mx = fmaxf(mx, s[amt][nt][r]);
            mx = fmaxf(mx, __shfl_xor(mx, 16));
            mx = fmaxf(mx, __shfl_xor(mx, 32));
            float sum = 0.f;
            #pragma unroll
            for (int amt = 0; amt < 4; ++amt)
                #pragma unroll
                for (int r = 0; r < 4; ++r) {
                    float p = __expf((s[amt][nt][r] - mx) * 0.18257418583505536f);
                    s[amt][nt][r] = p;
                    sum += p;
                }
            sum += __shfl_xor(sum, 16);
            sum += __shfl_xor(sum, 32);
            gsc[nt] = val_s[h * NK + 16 * nt + lr] / sum;
        }

        // --- attn^T = mfma(V^T, P^T): both operands packed in-lane ---
        f32x4 av[2][4];
        {
            bf16x8 Av[2][2];
            #pragma unroll
            for (int amt = 0; amt < 2; ++amt)
                #pragma unroll
                for (int kt = 0; kt < 2; ++kt) {
                    FU t;
                    t.u[0] = V32[2 * kt][amt][0];
                    t.u[1] = V32[2 * kt][amt][1];
                    t.u[2] = V32[2 * kt + 1][amt][0];
                    t.u[3] = V32[2 * kt + 1][amt][1];
                    Av[amt][kt] = t.f;
                }
            #pragma unroll
            for (int nt = 0; nt < 4; ++nt) {
                bf16x8 Pb[2];
                float g = gsc[nt];
                #pragma unroll
                for (int kt = 0; kt < 2; ++kt) {
                    FU t;
                    t.u[0] = pk2(s[2 * kt][nt][0] * g, s[2 * kt][nt][1] * g);
                    t.u[1] = pk2(s[2 * kt][nt][2] * g, s[2 * kt][nt][3] * g);
                    t.u[2] = pk2(s[2 * kt + 1][nt][0] * g, s[2 * kt + 1][nt][1] * g);
                    t.u[3] = pk2(s[2 * kt + 1][nt][2] * g, s[2 * kt + 1][nt][3] * g);
                    Pb[kt] = t.f;
                }
                #pragma unroll
                for (int amt = 0; amt < 2; ++amt) {
                    f32x4 a = (f32x4){0.f, 0.f, 0.f, 0.f};
                    a = __builtin_amdgcn_mfma_f32_16x16x32_bf16(Av[amt][0], Pb[0], a, 0, 0, 0);
                    a = __builtin_amdgcn_mfma_f32_16x16x32_bf16(Av[amt][1], Pb[1], a, 0, 0, 0);
                    av[amt][nt] = a;
                }
            }
        }
        // --- store attn to at_s[slot][d] (B-fragment-ready) ---
        unsigned* atw = (unsigned*)at_s;
        #pragma unroll
        for (int nt = 0; nt < 4; ++nt) {
            int base = (16 * nt + lr) * 18 + 2 * lg;
            #pragma unroll
            for (int amt = 0; amt < 2; ++amt) {
                atw[base + 8 * amt]     = pk2(av[amt][nt][0], av[amt][nt][1]);
                atw[base + 8 * amt + 1] = pk2(av[amt][nt][2], av[amt][nt][3]);
            }
        }
    }
    __syncthreads();

    // ====== Phase B: pre = attn @ Wcomb, fp32 LDS scatter, 4 passes =========
    // outf stride 49 floats: bank = (17*tok + 4*lg) % 32 -> near-uniform
    // (stride 48 was 8 banks -> deterministic 8-way conflicts, 8.7e7 cycles).
    float* outf = (float*)(sm + QK_BASE);  // [256][49] f32 = 50176 B
    for (int p = 0; p < 4; ++p) {
        for (int f = tid; f < 256 * 49; f += 384) outf[f] = 0.f;
        __syncthreads();
        if ((wv / 3) == (p & 1)) {
            const int wcol = wv % 3;
            #pragma unroll 1
            for (int h = 0; h < NE; ++h) {
                const unsigned short* at_h = (const unsigned short*)(sm + AT_BASE + h * 4608);
                bf16x8 Aw = ld8(Wcomb_t + ((long)h * 192 + p * 48 + 16 * wcol + lr) * 32 + 4 * lg);
                #pragma unroll
                for (int nt = 0; nt < 4; ++nt) {
                    bf16x8 Bt = ld8(at_h + (16 * nt + lr) * 36 + 4 * lg);
                    f32x4 acc = __builtin_amdgcn_mfma_f32_16x16x32_bf16(
                        Aw, Bt, (f32x4){0.f, 0.f, 0.f, 0.f}, 0, 0, 0);
                    int tok = idx_s[h * NK + 16 * nt + lr];
                    // races: waves -> disjoint 16-col slices; same wave: same lg
                    // -> distinct toks, diff lg -> distinct cols. RMW safe.
                    float* dst = outf + tok * 49 + 16 * wcol + 4 * lg;
                    dst[0] += acc[0];
                    dst[1] += acc[1];
                    dst[2] += acc[2];
                    dst[3] += acc[3];
                }
            }
        }
        __syncthreads();
        const int cl2 = (p == 3) ? 18 : 24;  // float2 cols this pass (c<180)
        for (int f = tid; f < 256 * cl2; f += 384) {
            int t = f / cl2, j = f % cl2;
            int c = 48 * p + 2 * j;
            float2 o;
            o.x = outf[t * 49 + 2 * j]     + bp[c];
            o.y = outf[t * 49 + 2 * j + 1] + bp[c + 1];
            long obase = (((long)b * NH + hb * 16 + (t >> 4)) * NW + wb * 16 + (t & 15)) * NC + c;
            *(float2*)(out + obase) = o;
        }
        __syncthreads();
    }
}

// ---------------------------------------------------------------------------
extern "C" void kernel_launch(void* const* d_in, const int* in_sizes, int n_in,
                              void* d_out, int out_size, void* d_ws, size_t ws_size,
                              hipStream_t stream) {
    const float* x    = (const float*)d_in[0];
    const float* Wr   = (const float*)d_in[1];
    const float* Wqkv = (const float*)d_in[2];
    const float* Wo   = (const float*)d_in[3];
    const float* Wp   = (const float*)d_in[4];
    const float* bp   = (const float*)d_in[5];
    float* out = (float*)d_out;

    char* ws = (char*)d_ws;
    unsigned short* Wqkv_t  = (unsigned short*)ws;                  // 221184 B
    unsigned short* Wcomb_t = (unsigned short*)(ws + 221184);       // 73728 B
    int*   idx_g  = (int*)(ws + 294912);                            // 3 MB
    float* vals_g = (float*)(ws + 294912 + (size_t)NWIN * NE * NK * 4);

    k_prep<<<432, 256, 0, stream>>>(Wqkv, Wo, Wp, Wqkv_t, Wcomb_t);
    k_router_topk<<<NWIN, 256, 0, stream>>>(x, Wr, idx_g, vals_g);
    k_fused<<<NWIN, 384, LDS_TOTAL, stream>>>(x, Wqkv_t, Wcomb_t, bp,
                                              idx_g, vals_g, out);
}

// Round 9
// 842.638 us; speedup vs baseline: 12.9839x; 1.0057x over previous
//
#include <hip/hip_runtime.h>
#include <math.h>

#define NB 8
#define NH 256
#define NW 256
#define NC 180
#define NE 6
#define HD 30
#define NL 256
#define NK 64
#define NWIN 2048

typedef __attribute__((ext_vector_type(8))) short bf16x8;
typedef __attribute__((ext_vector_type(4))) float f32x4;

union FU { bf16x8 f; unsigned u[4]; unsigned short s[8]; };

static __device__ __forceinline__ unsigned short f2bf(float x) {
    unsigned u = __float_as_uint(x);
    unsigned r = (u + 0x7FFFu + ((u >> 16) & 1u)) >> 16;
    return (unsigned short)r;
}
static __device__ __forceinline__ unsigned pk2(float a, float b) {
    return (unsigned)f2bf(a) | ((unsigned)f2bf(b) << 16);
}
static __device__ __forceinline__ float bf2f(unsigned short h) {
    return __uint_as_float(((unsigned)h) << 16);
}
// fragment load: elements {p[0..3], p[16..19]} — 8B-aligned rows
static __device__ __forceinline__ bf16x8 ld8(const unsigned short* p) {
    FU t;
    *(uint2*)&t.u[0] = *(const uint2*)p;
    *(uint2*)&t.u[2] = *(const uint2*)(p + 16);
    return t.f;
}
// same element order, 4B-aligned rows (stride-34 LDS)
static __device__ __forceinline__ bf16x8 ld8q(const unsigned short* p) {
    FU t;
    t.u[0] = *(const unsigned*)p;
    t.u[1] = *(const unsigned*)(p + 2);
    t.u[2] = *(const unsigned*)(p + 16);
    t.u[3] = *(const unsigned*)(p + 18);
    return t.f;
}
static __device__ __forceinline__ bf16x8 pack8(float4 a, float4 b) {
    FU t;
    t.u[0] = pk2(a.x, a.y); t.u[1] = pk2(a.z, a.w);
    t.u[2] = pk2(b.x, b.y); t.u[3] = pk2(b.z, b.w);
    return t.f;
}

// ---------------------------------------------------------------------------
// prep: Wqkv_t[h][n'<96][k<192] (n' = sec*32+r, n = sec*30+r; pads zero)
//       Wcomb_t[h][o<192][d<32] = (Wo[h] @ Wp^T)^T  (pads zero)
// ---------------------------------------------------------------------------
__global__ __launch_bounds__(256) void k_prep(
    const float* __restrict__ Wqkv, const float* __restrict__ Wo,
    const float* __restrict__ Wp,
    unsigned short* __restrict__ Wqkv_t, unsigned short* __restrict__ Wcomb_t)
{
    int i = blockIdx.x * 256 + threadIdx.x;
    if (i < NE * 96 * 192) {
        int h = i / (96 * 192), rm = i % (96 * 192), np = rm / 192, k = rm % 192;
        int sec = np >> 5, r = np & 31;
        float v = (r < 30 && k < NC) ? Wqkv[((long)h * NC + k) * 90 + sec * 30 + r] : 0.f;
        Wqkv_t[i] = f2bf(v);
    }
    if (i < NE * 192 * 32) {
        int h = i / (192 * 32), rm = i % (192 * 32), o = rm / 32, d = rm & 31;
        float acc = 0.f;
        if (o < NC && d < HD) {
            const float* wo = Wo + ((long)h * HD + d) * NC;
            const float* wp = Wp + (long)o * NC;
            for (int c = 0; c < NC; ++c) acc += wo[c] * wp[c];
        }
        Wcomb_t[i] = f2bf(acc);
    }
}

// ---------------------------------------------------------------------------
// Router: VERBATIM round-1 kernel (passed at 2.4e-4 => its compiled logit &
// sigmoid bits match the np reference's selection exactly). Do not touch.
// ---------------------------------------------------------------------------
__global__ __launch_bounds__(256) void k_router_topk(
    const float* __restrict__ x, const float* __restrict__ Wr,
    int* __restrict__ idx_g, float* __restrict__ vals_g)
{
    __shared__ float wr_s[NE * NC];
    __shared__ float xs[32 * 181];
    __shared__ float lg[NE * NL];

    const int w   = blockIdx.x;
    const int tid = threadIdx.x;
    const int b = w >> 8, hb = (w >> 4) & 15, wb = w & 15;
    const long win_base = (((long)b * NH + hb * 16) * NW + wb * 16) * NC;

    for (int f = tid; f < NE * NC; f += 256) wr_s[f] = Wr[f];
    __syncthreads();

    for (int tile = 0; tile < 8; ++tile) {
        for (int f = tid; f < 32 * NC; f += 256) {
            int tl = f / NC, ch = f % NC;
            int tok = tile * 32 + tl;
            int r = tok >> 4, cl = tok & 15;
            xs[tl * 181 + ch] = x[win_base + ((long)r * NW + cl) * NC + ch];
        }
        __syncthreads();
        if (tid < 192) {
            int tl = tid & 31, e = tid >> 5;
            float acc = 0.f;
            for (int c = 0; c < NC; ++c) acc += xs[tl * 181 + c] * wr_s[e * NC + c];
            lg[e * NL + tile * 32 + tl] = 1.0f / (1.0f + expf(-acc));
        }
        __syncthreads();
    }

    for (int e = 0; e < NE; ++e) {
        float vt = lg[e * NL + tid];
        if (tid == 0) {
            idx_g[(w * NE + e) * NK]  = 0;
            vals_g[(w * NE + e) * NK] = vt;
        } else {
            int rank = 0;
            for (int j = 1; j < NL; ++j) {
                float vj = lg[e * NL + j];
                rank += (vj > vt) || (vj == vt && j < tid);
            }
            if (rank < NK - 1) {
                idx_g[(w * NE + e) * NK + 1 + rank]  = tid;
                vals_g[(w * NE + e) * NK + 1 + rank] = vt;
            }
        }
    }
}

// ---------------------------------------------------------------------------
// fused: per-head attention (wave=head, in-register softmax)
//        -> comb GEMM + fp32 LDS scatter -> out + bias
// LDS (bytes): 0: q/k per head (h*8704; q 4352 + k 4352, stride 34 u16)
//                 [overlay phase B: outf f32[256][49] = 50176]
//              52224: at_s[h] = +h*4352 (u16 [64][34])
//              78336: idx u8[384]; 78720: val bf16[384] (768 B)
//              total 79488  (<= 39*2048: two blocks/CU must fit)
// ---------------------------------------------------------------------------
#define QK_BASE 0
#define AT_BASE 52224
#define IDX_BASE 78336
#define VAL_BASE 78720
#define LDS_TOTAL 79488

__global__ __launch_bounds__(384, 3) void k_fused(
    const float* __restrict__ x,
    const unsigned short* __restrict__ Wqkv_t,
    const unsigned short* __restrict__ Wcomb_t,
    const float* __restrict__ bp,
    const int* __restrict__ idx_g, const float* __restrict__ vals_g,
    float* __restrict__ out)
{
    extern __shared__ char sm[];
    const int w = blockIdx.x;
    const int tid = threadIdx.x;
    const int b = w >> 8, hb = (w >> 4) & 15, wb = w & 15;
    const long win_base = (((long)b * NH + hb * 16) * NW + wb * 16) * NC;

    const int wv = tid >> 6;
    const int ln = tid & 63;
    const int lr = ln & 15;
    const int lg = ln >> 4;

    unsigned char*  idx_s = (unsigned char*)(sm + IDX_BASE);
    unsigned short* val_s = (unsigned short*)(sm + VAL_BASE);

    // ---- load selection from the verbatim-router's output ----
    for (int f = tid; f < NE * NK; f += 384) {
        idx_s[f] = (unsigned char)idx_g[(long)w * NE * NK + f];
        val_s[f] = f2bf(vals_g[(long)w * NE * NK + f]);
    }
    __syncthreads();

    // ================= Phase A: attention, wave = head =======================
    {
        const int h = wv;
        unsigned short* q_s = (unsigned short*)(sm + QK_BASE + h * 8704);
        unsigned short* k_s = q_s + 2176;
        unsigned short* at_s = (unsigned short*)(sm + AT_BASE + h * 4352);

        // --- QKV = gather(x) @ Wqkv_t : M=64, N=96, K=192 ---
        // kt-outer / nt-inner: acc[6][4] lives in AGPRs, A-frags transient.
        const float* xr[4];
        #pragma unroll
        for (int mt = 0; mt < 4; ++mt) {
            int tok = idx_s[h * NK + 16 * mt + lr];
            xr[mt] = x + win_base + ((long)(tok >> 4) * NW + (tok & 15)) * NC;
        }
        f32x4 acc[6][4];
        #pragma unroll
        for (int nt = 0; nt < 6; ++nt)
            #pragma unroll
            for (int mt = 0; mt < 4; ++mt) acc[nt][mt] = (f32x4){0.f, 0.f, 0.f, 0.f};

        const unsigned short* bb = Wqkv_t + ((long)h * 96 + lr) * 192 + 4 * lg;
        #pragma unroll
        for (int kt = 0; kt < 6; ++kt) {
            bf16x8 Amt[4];
            #pragma unroll
            for (int mt = 0; mt < 4; ++mt) {
                if (kt < 5) {
                    float4 a  = *(const float4*)(xr[mt] + 4 * lg + 32 * kt);
                    float4 b2 = *(const float4*)(xr[mt] + 4 * lg + 32 * kt + 16);
                    Amt[mt] = pack8(a, b2);
                } else {
                    float4 a  = *(const float4*)(xr[mt] + 4 * lg + 160);
                    float4 b2 = make_float4(0.f, 0.f, 0.f, 0.f);
                    if (lg == 0) b2 = *(const float4*)(xr[mt] + 176);
                    Amt[mt] = pack8(a, b2);
                }
            }
            #pragma unroll
            for (int nt = 0; nt < 6; ++nt) {
                bf16x8 B = ld8(bb + nt * (16 * 192) + kt * 32);
                #pragma unroll
                for (int mt = 0; mt < 4; ++mt)
                    acc[nt][mt] = __builtin_amdgcn_mfma_f32_16x16x32_bf16(Amt[mt], B, acc[nt][mt], 0, 0, 0);
            }
        }

        // --- write Q/K (nt 0..3) to LDS transpose buffers ---
        #pragma unroll
        for (int nt = 0; nt < 4; ++nt) {
            unsigned short* dst = (nt < 2 ? q_s : k_s) + 16 * (nt & 1) + lr;
            #pragma unroll
            for (int mt = 0; mt < 4; ++mt) {
                int row = 16 * mt + 4 * lg;
                dst[(row + 0) * 34] = f2bf(acc[nt][mt][0]);
                dst[(row + 1) * 34] = f2bf(acc[nt][mt][1]);
                dst[(row + 2) * 34] = f2bf(acc[nt][mt][2]);
                dst[(row + 3) * 34] = f2bf(acc[nt][mt][3]);
            }
        }
        // --- keep V (nt 4,5) in registers ---
        unsigned V32[4][2][2];
        #pragma unroll
        for (int j = 0; j < 2; ++j)
            #pragma unroll
            for (int mt = 0; mt < 4; ++mt) {
                V32[mt][j][0] = pk2(acc[4 + j][mt][0], acc[4 + j][mt][1]);
                V32[mt][j][1] = pk2(acc[4 + j][mt][2], acc[4 + j][mt][3]);
            }

        // BARRIER: the u16 ds_writes above and the u32 ds_reads below are
        // "no-alias" under TBAA, so without a barrier the compiler may hoist
        // the reads above the writes (round-7 NaN). __syncthreads() pins order.
        __syncthreads();

        // --- scores^T = mfma(K, Q): lane holds col q=16nt+lr, rows k ---
        f32x4 s[4][4];
        {
            bf16x8 Bq[4];
            #pragma unroll
            for (int nt = 0; nt < 4; ++nt)
                Bq[nt] = ld8q(q_s + (16 * nt + lr) * 34 + 4 * lg);
            #pragma unroll
            for (int amt = 0; amt < 4; ++amt) {
                bf16x8 Ak = ld8q(k_s + (16 * amt + lr) * 34 + 4 * lg);
                #pragma unroll
                for (int nt = 0; nt < 4; ++nt)
                    s[amt][nt] = __builtin_amdgcn_mfma_f32_16x16x32_bf16(
                        Ak, Bq[nt], (f32x4){0.f, 0.f, 0.f, 0.f}, 0, 0, 0);
            }
        }

        // --- in-register softmax over k (rows) per q-column + gate ---
        float gsc[4];
        #pragma unroll
        for (int nt = 0; nt < 4; ++nt) {
            float mx = -1e30f;
            #pragma unroll
            for (int amt = 0; amt < 4; ++amt)
                #pragma unroll
                for (int r = 0; r < 4; ++r) mx = fmaxf(mx, s[amt][nt][r]);
            mx = fmaxf(mx, __shfl_xor(mx, 16));
            mx = fmaxf(mx, __shfl_xor(mx, 32));
            float sum = 0.f;
            #pragma unroll
            for (int amt = 0; amt < 4; ++amt)
                #pragma unroll
                for (int r = 0; r < 4; ++r) {
                    float p = __expf((s[amt][nt][r] - mx) * 0.18257418583505536f);
                    s[amt][nt][r] = p;
                    sum += p;
                }
            sum += __shfl_xor(sum, 16);
            sum += __shfl_xor(sum, 32);
            gsc[nt] = bf2f(val_s[h * NK + 16 * nt + lr]) / sum;
        }

        // --- attn^T = mfma(V^T, P^T): both operands packed in-lane ---
        f32x4 av[2][4];
        {
            bf16x8 Av[2][2];
            #pragma unroll
            for (int amt = 0; amt < 2; ++amt)
                #pragma unroll
                for (int kt = 0; kt < 2; ++kt) {
                    FU t;
                    t.u[0] = V32[2 * kt][amt][0];
                    t.u[1] = V32[2 * kt][amt][1];
                    t.u[2] = V32[2 * kt + 1][amt][0];
                    t.u[3] = V32[2 * kt + 1][amt][1];
                    Av[amt][kt] = t.f;
                }
            #pragma unroll
            for (int nt = 0; nt < 4; ++nt) {
                bf16x8 Pb[2];
                float g = gsc[nt];
                #pragma unroll
                for (int kt = 0; kt < 2; ++kt) {
                    FU t;
                    t.u[0] = pk2(s[2 * kt][nt][0] * g, s[2 * kt][nt][1] * g);
                    t.u[1] = pk2(s[2 * kt][nt][2] * g, s[2 * kt][nt][3] * g);
                    t.u[2] = pk2(s[2 * kt + 1][nt][0] * g, s[2 * kt + 1][nt][1] * g);
                    t.u[3] = pk2(s[2 * kt + 1][nt][2] * g, s[2 * kt + 1][nt][3] * g);
                    Pb[kt] = t.f;
                }
                #pragma unroll
                for (int amt = 0; amt < 2; ++amt) {
                    f32x4 a = (f32x4){0.f, 0.f, 0.f, 0.f};
                    a = __builtin_amdgcn_mfma_f32_16x16x32_bf16(Av[amt][0], Pb[0], a, 0, 0, 0);
                    a = __builtin_amdgcn_mfma_f32_16x16x32_bf16(Av[amt][1], Pb[1], a, 0, 0, 0);
                    av[amt][nt] = a;
                }
            }
        }
        // --- store attn to at_s[slot][d] (stride 34 u16 = 17 u32) ---
        unsigned* atw = (unsigned*)at_s;
        #pragma unroll
        for (int nt = 0; nt < 4; ++nt) {
            int base = (16 * nt + lr) * 17 + 2 * lg;
            #pragma unroll
            for (int amt = 0; amt < 2; ++amt) {
                atw[base + 8 * amt]     = pk2(av[amt][nt][0], av[amt][nt][1]);
                atw[base + 8 * amt + 1] = pk2(av[amt][nt][2], av[amt][nt][3]);
            }
        }
    }
    __syncthreads();

    // ====== Phase B: pre = attn @ Wcomb, fp32 LDS scatter, 4 passes =========
    // outf stride 49 floats: bank = (17*tok + 4*lg) % 32 -> near-uniform.
    float* outf = (float*)(sm + QK_BASE);  // [256][49] f32 = 50176 B
    for (int p = 0; p < 4; ++p) {
        for (int f = tid; f < 256 * 49; f += 384) outf[f] = 0.f;
        __syncthreads();
        if ((wv / 3) == (p & 1)) {
            const int wcol = wv % 3;
            #pragma unroll 1
            for (int h = 0; h < NE; ++h) {
                const unsigned short* at_h = (const unsigned short*)(sm + AT_BASE + h * 4352);
                bf16x8 Aw = ld8(Wcomb_t + ((long)h * 192 + p * 48 + 16 * wcol + lr) * 32 + 4 * lg);
                #pragma unroll
                for (int nt = 0; nt < 4; ++nt) {
                    bf16x8 Bt = ld8q(at_h + (16 * nt + lr) * 34 + 4 * lg);
                    f32x4 acc = __builtin_amdgcn_mfma_f32_16x16x32_bf16(
                        Aw, Bt, (f32x4){0.f, 0.f, 0.f, 0.f}, 0, 0, 0);
                    int tok = idx_s[h * NK + 16 * nt + lr];
                    // races: waves -> disjoint 16-col slices; same wave: same lg
                    // -> distinct toks, diff lg -> distinct cols. RMW safe.
                    float* dst = outf + tok * 49 + 16 * wcol + 4 * lg;
                    dst[0] += acc[0];
                    dst[1] += acc[1];
                    dst[2] += acc[2];
                    dst[3] += acc[3];
                }
            }
        }
        __syncthreads();
        const int cl2 = (p == 3) ? 18 : 24;  // float2 cols this pass (c<180)
        for (int f = tid; f < 256 * cl2; f += 384) {
            int t = f / cl2, j = f % cl2;
            int c = 48 * p + 2 * j;
            float2 o;
            o.x = outf[t * 49 + 2 * j]     + bp[c];
            o.y = outf[t * 49 + 2 * j + 1] + bp[c + 1];
            long obase = (((long)b * NH + hb * 16 + (t >> 4)) * NW + wb * 16 + (t & 15)) * NC + c;
            *(float2*)(out + obase) = o;
        }
        __syncthreads();
    }
}

// ---------------------------------------------------------------------------
extern "C" void kernel_launch(void* const* d_in, const int* in_sizes, int n_in,
                              void* d_out, int out_size, void* d_ws, size_t ws_size,
                              hipStream_t stream) {
    const float* x    = (const float*)d_in[0];
    const float* Wr   = (const float*)d_in[1];
    const float* Wqkv = (const float*)d_in[2];
    const float* Wo   = (const float*)d_in[3];
    const float* Wp   = (const float*)d_in[4];
    const float* bp   = (const float*)d_in[5];
    float* out = (float*)d_out;

    char* ws = (char*)d_ws;
    unsigned short* Wqkv_t  = (unsigned short*)ws;                  // 221184 B
    unsigned short* Wcomb_t = (unsigned short*)(ws + 221184);       // 73728 B
    int*   idx_g  = (int*)(ws + 294912);                            // 3 MB
    float* vals_g = (float*)(ws + 294912 + (size_t)NWIN * NE * NK * 4);

    k_prep<<<432, 256, 0, stream>>>(Wqkv, Wo, Wp, Wqkv_t, Wcomb_t);
    k_router_topk<<<NWIN, 256, 0, stream>>>(x, Wr, idx_g, vals_g);
    k_fused<<<NWIN, 384, LDS_TOTAL, stream>>>(x, Wqkv_t, Wcomb_t, bp,
                                              idx_g, vals_g, out);
}